// Round 1
// baseline (900.188 us; speedup 1.0000x reference)
//
#include <hip/hip_runtime.h>
#include <hip/hip_bf16.h>
#include <math.h>

namespace {
constexpr int Bc = 64, Nc = 2048, Dc = 256, Hc = 8, DHc = 32, Sc = 10;
constexpr float kNeg = -1000000000.0f;
constexpr float kClip = 10.0f;
constexpr float kScale = 0.17677669529663687f;   // 1/sqrt(32)
constexpr float kScale2 = 0.0625f;               // 1/sqrt(256)
}

// ---- h_mean = mean over N, chunked partials (coalesced: thread = d) ----
__global__ __launch_bounds__(256) void k_hmean_part(const float* __restrict__ enc,
                                                    float* __restrict__ hpart) {
  int b = blockIdx.x >> 3, c = blockIdx.x & 7, d = threadIdx.x;
  const float* p = enc + ((size_t)b * Nc + c * 256) * Dc + d;
  float s = 0.f;
  for (int n = 0; n < 256; ++n) s += p[(size_t)n * Dc];
  hpart[(size_t)blockIdx.x * Dc + d] = s;
}

__global__ __launch_bounds__(256) void k_hmean_red(const float* __restrict__ hpart,
                                                   float* __restrict__ hmean) {
  int b = blockIdx.x, d = threadIdx.x;
  float s = 0.f;
  for (int c = 0; c < 8; ++c) s += hpart[(size_t)(b * 8 + c) * Dc + d];
  hmean[b * Dc + d] = s * (1.0f / Nc);
}

// ---- q = hmean@Wq^T + bq ; g[b,h,:] = q_h^T Wk_h ; c[b,h] = q_h . bk_h ----
__global__ __launch_bounds__(256) void k_qgc(const float* __restrict__ hmean,
                                             const float* __restrict__ w_in,
                                             const float* __restrict__ b_in,
                                             float* __restrict__ g, float* __restrict__ c) {
  int b = blockIdx.x, t = threadIdx.x;
  __shared__ float hm[Dc];
  __shared__ float qsh[Dc];
  hm[t] = hmean[b * Dc + t];
  __syncthreads();
  {
    const float* row = w_in + (size_t)t * Dc;  // Wq row t
    float acc = b_in[t];
    for (int d = 0; d < Dc; ++d) acc += row[d] * hm[d];
    qsh[t] = acc;
  }
  __syncthreads();
  // thread t = output dim d of g
  for (int h = 0; h < Hc; ++h) {
    float acc = 0.f;
    const float* wk = w_in + (size_t)(Dc + h * DHc) * Dc + t;  // Wk rows, col t
    const float* qh = qsh + h * DHc;
    #pragma unroll 8
    for (int i = 0; i < DHc; ++i) acc += qh[i] * wk[(size_t)i * Dc];
    g[((size_t)b * Hc + h) * Dc + t] = acc;
  }
  if (t < Hc) {
    float acc = 0.f;
    for (int i = 0; i < DHc; ++i) acc += qsh[t * DHc + i] * b_in[Dc + t * DHc + i];
    c[b * Hc + t] = acc;
  }
}

// ---- s[b,h,n] = scale*(g[b,h,:].enc[b,n,:] + c[b,h]) ; wave per n ----
__global__ __launch_bounds__(256) void k_scores(const float* __restrict__ enc,
                                                const float* __restrict__ g,
                                                const float* __restrict__ c,
                                                float* __restrict__ s) {
  int b = blockIdx.x >> 9;       // 512 blocks per b
  int nb = blockIdx.x & 511;
  int wave = threadIdx.x >> 6, lane = threadIdx.x & 63;
  __shared__ __align__(16) float gsm[Hc * Dc];
  __shared__ float csm[Hc];
  for (int k = threadIdx.x; k < Hc * Dc; k += 256) gsm[k] = g[(size_t)b * Hc * Dc + k];
  if (threadIdx.x < Hc) csm[threadIdx.x] = c[b * Hc + threadIdx.x];
  __syncthreads();
  int n = nb * 4 + wave;
  const float4 e = *reinterpret_cast<const float4*>(enc + ((size_t)b * Nc + n) * Dc + lane * 4);
  float pd[Hc];
  #pragma unroll
  for (int h = 0; h < Hc; ++h) {
    const float4 gg = *reinterpret_cast<const float4*>(gsm + h * Dc + lane * 4);
    pd[h] = e.x * gg.x + e.y * gg.y + e.z * gg.z + e.w * gg.w;
  }
  #pragma unroll
  for (int off = 32; off >= 1; off >>= 1) {
    #pragma unroll
    for (int h = 0; h < Hc; ++h) pd[h] += __shfl_xor(pd[h], off);
  }
  if (lane == 0) {
    #pragma unroll
    for (int h = 0; h < Hc; ++h)
      s[((size_t)b * Hc + h) * Nc + n] = kScale * (pd[h] + csm[h]);
  }
}

// ---- per (b,h): m = max_n s ----
__global__ __launch_bounds__(256) void k_rowmax(const float* __restrict__ s,
                                                float* __restrict__ mrow) {
  int bh = blockIdx.x, t = threadIdx.x;
  __shared__ float red[256];
  float v = -3.0e38f;
  for (int k = t; k < Nc; k += 256) v = fmaxf(v, s[(size_t)bh * Nc + k]);
  red[t] = v;
  __syncthreads();
  for (int off = 128; off >= 1; off >>= 1) {
    if (t < off) red[t] = fmaxf(red[t], red[t + off]);
    __syncthreads();
  }
  if (t == 0) mrow[bh] = red[0];
}

// ---- w = exp(s-m) ; W0 = sum w ----
__global__ __launch_bounds__(256) void k_weights(const float* __restrict__ s,
                                                 const float* __restrict__ mrow,
                                                 float* __restrict__ w, float* __restrict__ W0) {
  int bh = blockIdx.x, t = threadIdx.x;
  __shared__ float red[256];
  float m = mrow[bh];
  float acc = 0.f;
  for (int k = t; k < Nc; k += 256) {
    float e = expf(s[(size_t)bh * Nc + k] - m);
    w[(size_t)bh * Nc + k] = e;
    acc += e;
  }
  red[t] = acc;
  __syncthreads();
  for (int off = 128; off >= 1; off >>= 1) {
    if (t < off) red[t] += red[t + off];
    __syncthreads();
  }
  if (t == 0) W0[bh] = red[0];
}

// ---- S0 partials: Spart[b,c,h,d] = sum_{n in chunk c} w[b,h,n]*enc[b,n,d] ----
__global__ __launch_bounds__(256) void k_S0part(const float* __restrict__ enc,
                                                const float* __restrict__ w,
                                                float* __restrict__ Spart) {
  int b = blockIdx.x >> 3, cid = blockIdx.x & 7, t = threadIdx.x;
  __shared__ float wsm[Hc * 256];
  for (int k = t; k < Hc * 256; k += 256) {
    int h = k >> 8, ni = k & 255;
    wsm[k] = w[((size_t)b * Hc + h) * Nc + cid * 256 + ni];
  }
  __syncthreads();
  float acc[Hc] = {};
  const float* ep = enc + ((size_t)b * Nc + cid * 256) * Dc + t;
  for (int ni = 0; ni < 256; ++ni) {
    float ev = ep[(size_t)ni * Dc];
    #pragma unroll
    for (int h = 0; h < Hc; ++h) acc[h] += wsm[h * 256 + ni] * ev;
  }
  #pragma unroll
  for (int h = 0; h < Hc; ++h)
    Spart[(((size_t)b * 8 + cid) * Hc + h) * Dc + t] = acc[h];
}

__global__ __launch_bounds__(256) void k_S0red(const float* __restrict__ Spart,
                                               const float* __restrict__ W0,
                                               float* __restrict__ Sacc, float* __restrict__ Wrun) {
  int b = blockIdx.x >> 3, h = blockIdx.x & 7, t = threadIdx.x;
  float acc = 0.f;
  for (int cid = 0; cid < 8; ++cid)
    acc += Spart[(((size_t)b * 8 + cid) * Hc + h) * Dc + t];
  Sacc[((size_t)b * Hc + h) * Dc + t] = acc;
  if (t == 0) Wrun[b * Hc + h] = W0[b * Hc + h];
}

// ---- remove newly-masked row j from Sacc / Wrun ----
__global__ __launch_bounds__(256) void k_update(const float* __restrict__ enc,
                                                const float* __restrict__ w,
                                                const int* __restrict__ selj,
                                                float* __restrict__ Sacc, float* __restrict__ Wrun) {
  int b = blockIdx.x, t = threadIdx.x;
  __shared__ float wj[Hc];
  __shared__ int jsh;
  if (t == 0) jsh = selj[b];
  __syncthreads();
  int j = jsh;
  if (t < Hc) wj[t] = w[((size_t)b * Hc + t) * Nc + j];
  __syncthreads();
  float ev = enc[((size_t)b * Nc + j) * Dc + t];
  #pragma unroll
  for (int h = 0; h < Hc; ++h)
    Sacc[((size_t)b * Hc + h) * Dc + t] -= wj[h] * ev;
  if (t < Hc) Wrun[b * Hc + t] -= wj[t];
}

// ---- ctx -> attn_out -> qs -> r, one block per b ----
__global__ __launch_bounds__(256) void k_chain(const float* __restrict__ Sacc,
                                               const float* __restrict__ Wrun,
                                               const float* __restrict__ w_in,
                                               const float* __restrict__ b_in,
                                               const float* __restrict__ out_w,
                                               const float* __restrict__ out_b,
                                               const float* __restrict__ sha_wq,
                                               const float* __restrict__ sha_wk,
                                               float* __restrict__ r) {
  int b = blockIdx.x, t = threadIdx.x;
  __shared__ float sa[Hc * Dc];
  __shared__ float va[Dc];
  __shared__ float vb[Dc];
  __shared__ float Wsh[Hc];
  for (int k = t; k < Hc * Dc; k += 256) sa[k] = Sacc[(size_t)b * Hc * Dc + k];
  if (t < Hc) Wsh[t] = Wrun[b * Hc + t];
  __syncthreads();
  {  // ctx[t] = Wv_row(t) . (Sacc_h / W_h) + bv[t]
    int h = t >> 5;
    const float* row = w_in + (size_t)(2 * Dc + t) * Dc;
    float acc = 0.f;
    #pragma unroll 4
    for (int d = 0; d < Dc; ++d) acc += row[d] * sa[h * Dc + d];
    va[t] = acc / Wsh[h] + b_in[2 * Dc + t];
  }
  __syncthreads();
  {  // attn_out
    const float* row = out_w + (size_t)t * Dc;
    float acc = 0.f;
    #pragma unroll 4
    for (int d = 0; d < Dc; ++d) acc += row[d] * va[d];
    vb[t] = acc + out_b[t];
  }
  __syncthreads();
  {  // qs
    const float* row = sha_wq + (size_t)t * Dc;
    float acc = 0.f;
    #pragma unroll 4
    for (int d = 0; d < Dc; ++d) acc += row[d] * vb[d];
    va[t] = acc;  // va fully consumed before prior sync
  }
  __syncthreads();
  {  // r[t] = sum_d' qs[d'] * sha_wk[d', t]  (coalesced over t)
    float acc = 0.f;
    #pragma unroll 4
    for (int dp = 0; dp < Dc; ++dp) acc += va[dp] * sha_wk[(size_t)dp * Dc + t];
    r[b * Dc + t] = acc;
  }
}

// ---- u[b,n] = 10*tanh(scale2 * r[b].enc[b,n]) ; wave per n, 8 n per wave ----
__global__ __launch_bounds__(256) void k_uscore(const float* __restrict__ enc,
                                                const float* __restrict__ r,
                                                float* __restrict__ u) {
  int b = blockIdx.x >> 6;  // 64 groups per b
  int ng = blockIdx.x & 63;
  int wave = threadIdx.x >> 6, lane = threadIdx.x & 63;
  const float4 rr = reinterpret_cast<const float4*>(r + b * Dc)[lane];
  int n0 = ng * 32 + wave * 8;
  for (int q = 0; q < 8; ++q) {
    int n = n0 + q;
    const float4 e = reinterpret_cast<const float4*>(enc + ((size_t)b * Nc + n) * Dc)[lane];
    float v = e.x * rr.x + e.y * rr.y + e.z * rr.z + e.w * rr.w;
    #pragma unroll
    for (int off = 32; off >= 1; off >>= 1) v += __shfl_xor(v, off);
    if (lane == 0) u[(size_t)b * Nc + n] = kClip * tanhf(kScale2 * v);
  }
}

// ---- masked log-softmax + argmax + entropy + outputs, one block per b ----
__global__ __launch_bounds__(256) void k_select(const float* __restrict__ u,
                                                int* __restrict__ mask, int* __restrict__ selj,
                                                float* __restrict__ out, int tstep) {
  int b = blockIdx.x, t = threadIdx.x;
  __shared__ float red[256];
  __shared__ int redi[256];
  float uval[8];
  float lmax = -3.0e38f;
  int lidx = 0;
  #pragma unroll
  for (int q = 0; q < 8; ++q) {
    int n = t + q * 256;
    float v = u[(size_t)b * Nc + n];
    if (mask[b * Nc + n]) v = kNeg;
    uval[q] = v;
    if (v > lmax) { lmax = v; lidx = n; }   // ascending n + strict > => first max
  }
  red[t] = lmax; redi[t] = lidx;
  __syncthreads();
  for (int off = 128; off >= 1; off >>= 1) {
    if (t < off) {
      float o = red[t + off]; int oi = redi[t + off];
      if (o > red[t] || (o == red[t] && oi < redi[t])) { red[t] = o; redi[t] = oi; }
    }
    __syncthreads();
  }
  float mu = red[0];
  int gidx = redi[0];
  __syncthreads();
  float ssum = 0.f;
  #pragma unroll
  for (int q = 0; q < 8; ++q) ssum += expf(uval[q] - mu);
  red[t] = ssum;
  __syncthreads();
  for (int off = 128; off >= 1; off >>= 1) {
    if (t < off) red[t] += red[t + off];
    __syncthreads();
  }
  float Z = red[0];
  float lse = mu + logf(Z);
  __syncthreads();
  float ent = 0.f;
  #pragma unroll
  for (int q = 0; q < 8; ++q) {
    float logp = uval[q] - lse;
    float p = expf(logp);
    if (p > 0.f) ent -= p * logp;
  }
  red[t] = ent;
  __syncthreads();
  for (int off = 128; off >= 1; off >>= 1) {
    if (t < off) red[t] += red[t + off];
    __syncthreads();
  }
  if (t == 0) {
    float enttot = red[0];
    float pi = expf(u[(size_t)b * Nc + gidx] - lse);
    out[b * Sc + tstep] = (float)gidx;
    out[Bc * Sc + b * Sc + tstep] = pi;
    if (tstep == 0) out[2 * Bc * Sc + b] = enttot;
    else out[2 * Bc * Sc + b] += enttot;
    selj[b] = gidx;
    mask[b * Nc + gidx] = 1;
  }
}

extern "C" void kernel_launch(void* const* d_in, const int* in_sizes, int n_in,
                              void* d_out, int out_size, void* d_ws, size_t ws_size,
                              hipStream_t stream) {
  (void)in_sizes; (void)n_in; (void)out_size; (void)ws_size;
  const float* enc  = (const float*)d_in[0];
  const float* in_w = (const float*)d_in[1];
  const float* in_b = (const float*)d_in[2];
  const float* ow   = (const float*)d_in[3];
  const float* ob   = (const float*)d_in[4];
  const float* swq  = (const float*)d_in[5];
  const float* swk  = (const float*)d_in[6];
  float* out = (float*)d_out;

  float* ws = (float*)d_ws;
  size_t off = 0;
  auto alloc = [&](size_t n) { float* p = ws + off; off += n; return p; };
  float* hpart = alloc((size_t)Bc * 8 * Dc);
  float* hmean = alloc((size_t)Bc * Dc);
  float* g     = alloc((size_t)Bc * Hc * Dc);
  float* c     = alloc((size_t)Bc * Hc);
  float* s     = alloc((size_t)Bc * Hc * Nc);
  float* mrow  = alloc((size_t)Bc * Hc);
  float* w     = alloc((size_t)Bc * Hc * Nc);
  float* W0    = alloc((size_t)Bc * Hc);
  float* Spart = alloc((size_t)Bc * 8 * Hc * Dc);
  float* Sacc  = alloc((size_t)Bc * Hc * Dc);
  float* Wrun  = alloc((size_t)Bc * Hc);
  float* r     = alloc((size_t)Bc * Dc);
  float* u     = alloc((size_t)Bc * Nc);
  int* mask    = (int*)alloc((size_t)Bc * Nc);
  int* selj    = (int*)alloc(Bc);

  k_hmean_part<<<Bc * 8, 256, 0, stream>>>(enc, hpart);
  k_hmean_red<<<Bc, 256, 0, stream>>>(hpart, hmean);
  k_qgc<<<Bc, 256, 0, stream>>>(hmean, in_w, in_b, g, c);
  k_scores<<<Bc * (Nc / 4), 256, 0, stream>>>(enc, g, c, s);
  k_rowmax<<<Bc * Hc, 256, 0, stream>>>(s, mrow);
  k_weights<<<Bc * Hc, 256, 0, stream>>>(s, mrow, w, W0);
  k_S0part<<<Bc * 8, 256, 0, stream>>>(enc, w, Spart);
  k_S0red<<<Bc * Hc, 256, 0, stream>>>(Spart, W0, Sacc, Wrun);
  hipMemsetAsync(mask, 0, (size_t)Bc * Nc * sizeof(int), stream);

  for (int t = 0; t < Sc; ++t) {
    if (t > 0) k_update<<<Bc, 256, 0, stream>>>(enc, w, selj, Sacc, Wrun);
    k_chain<<<Bc, 256, 0, stream>>>(Sacc, Wrun, in_w, in_b, ow, ob, swq, swk, r);
    k_uscore<<<Bc * (Nc / 32), 256, 0, stream>>>(enc, r, u);
    k_select<<<Bc, 256, 0, stream>>>(u, mask, selj, out, t);
  }
}

// Round 2
// 547.994 us; speedup vs baseline: 1.6427x; 1.6427x over previous
//
#include <hip/hip_runtime.h>
#include <hip/hip_bf16.h>
#include <math.h>

namespace {
constexpr int Bc = 64, Nc = 2048, Dc = 256, Hc = 8, DHc = 32, Sc = 10;
constexpr float kNeg = -1000000000.0f;
constexpr float kClip = 10.0f;
constexpr float kScale = 0.17677669529663687f;   // 1/sqrt(32)
constexpr float kScale2 = 0.0625f;               // 1/sqrt(256)
}

// ---- h_mean partials ----
__global__ __launch_bounds__(256) void k_hmean_part(const float* __restrict__ enc,
                                                    float* __restrict__ hpart) {
  int b = blockIdx.x >> 3, c = blockIdx.x & 7, d = threadIdx.x;
  const float* p = enc + ((size_t)b * Nc + c * 256) * Dc + d;
  float s = 0.f;
  for (int n = 0; n < 256; ++n) s += p[(size_t)n * Dc];
  hpart[(size_t)blockIdx.x * Dc + d] = s;
}

__global__ __launch_bounds__(256) void k_hmean_red(const float* __restrict__ hpart,
                                                   float* __restrict__ hmean) {
  int b = blockIdx.x, d = threadIdx.x;
  float s = 0.f;
  for (int c = 0; c < 8; ++c) s += hpart[(size_t)(b * 8 + c) * Dc + d];
  hmean[b * Dc + d] = s * (1.0f / Nc);
}

// ---- q = hmean@Wq^T + bq ; g[b,h,:] = q_h^T Wk_h ; c[b,h] = q_h . bk_h ----
__global__ __launch_bounds__(256) void k_qgc(const float* __restrict__ hmean,
                                             const float* __restrict__ w_in,
                                             const float* __restrict__ b_in,
                                             float* __restrict__ g, float* __restrict__ c) {
  int b = blockIdx.x, t = threadIdx.x;
  __shared__ float hm[Dc];
  __shared__ float qsh[Dc];
  hm[t] = hmean[b * Dc + t];
  __syncthreads();
  {
    const float* row = w_in + (size_t)t * Dc;  // Wq row t
    float acc = b_in[t];
    for (int d = 0; d < Dc; ++d) acc += row[d] * hm[d];
    qsh[t] = acc;
  }
  __syncthreads();
  for (int h = 0; h < Hc; ++h) {
    float acc = 0.f;
    const float* wk = w_in + (size_t)(Dc + h * DHc) * Dc + t;  // Wk rows, col t
    const float* qh = qsh + h * DHc;
    #pragma unroll 8
    for (int i = 0; i < DHc; ++i) acc += qh[i] * wk[(size_t)i * Dc];
    g[((size_t)b * Hc + h) * Dc + t] = acc;
  }
  if (t < Hc) {
    float acc = 0.f;
    for (int i = 0; i < DHc; ++i) acc += qsh[t * DHc + i] * b_in[Dc + t * DHc + i];
    c[b * Hc + t] = acc;
  }
}

// ---- setup: M1 = sha_wq @ out_w ; m1b = sha_wq @ out_b ----
__global__ __launch_bounds__(256) void k_A1(const float* __restrict__ swq,
                                            const float* __restrict__ ow,
                                            const float* __restrict__ ob,
                                            float* __restrict__ M1, float* __restrict__ m1b) {
  int i = blockIdx.x, e = threadIdx.x;
  __shared__ float row[Dc];
  __shared__ float red[256];
  row[e] = swq[(size_t)i * Dc + e];
  __syncthreads();
  float acc = 0.f;
  #pragma unroll 4
  for (int k = 0; k < Dc; ++k) acc += row[k] * ow[(size_t)k * Dc + e];
  M1[(size_t)i * Dc + e] = acc;
  red[e] = row[e] * ob[e];
  __syncthreads();
  for (int off = 128; off >= 1; off >>= 1) {
    if (e < off) red[e] += red[e + off];
    __syncthreads();
  }
  if (e == 0) m1b[i] = red[0];
}

// ---- setup: A = sha_wk^T @ M1 ; cvec = A@bv + sha_wk^T@m1b ----
__global__ __launch_bounds__(256) void k_A2(const float* __restrict__ swk,
                                            const float* __restrict__ M1,
                                            const float* __restrict__ m1b,
                                            const float* __restrict__ b_in,
                                            float* __restrict__ Aout, float* __restrict__ cvec) {
  int d = blockIdx.x, e = threadIdx.x;
  __shared__ float col[Dc];
  __shared__ float red[256];
  col[e] = swk[(size_t)e * Dc + d];
  __syncthreads();
  float acc = 0.f;
  #pragma unroll 4
  for (int k = 0; k < Dc; ++k) acc += col[k] * M1[(size_t)k * Dc + e];
  Aout[(size_t)d * Dc + e] = acc;
  red[e] = acc * b_in[2 * Dc + e] + col[e] * m1b[e];
  __syncthreads();
  for (int off = 128; off >= 1; off >>= 1) {
    if (e < off) red[e] += red[e + off];
    __syncthreads();
  }
  if (e == 0) cvec[d] = red[0];
}

// ---- setup: BT[(h*256+e)*256+d] = sum_i A[d][h*32+i] * Wv[h*32+i][e] ----
__global__ __launch_bounds__(256) void k_A3(const float* __restrict__ Aout,
                                            const float* __restrict__ w_in,
                                            float* __restrict__ BT) {
  int h = blockIdx.x >> 3, et = blockIdx.x & 7, d = threadIdx.x;
  float arow[DHc];
  #pragma unroll
  for (int i = 0; i < DHc; ++i) arow[i] = Aout[(size_t)d * Dc + h * DHc + i];
  __shared__ float wv[DHc][DHc];
  for (int k = threadIdx.x; k < DHc * DHc; k += 256) {
    int i = k >> 5, j = k & 31;
    wv[i][j] = w_in[(size_t)(2 * Dc + h * DHc + i) * Dc + et * DHc + j];
  }
  __syncthreads();
  for (int j = 0; j < DHc; ++j) {
    float acc = 0.f;
    #pragma unroll
    for (int i = 0; i < DHc; ++i) acc += arow[i] * wv[i][j];
    BT[((size_t)h * Dc + et * DHc + j) * Dc + d] = acc;
  }
}

// ---- scores: thread-owns-n, LDS tile stride 33 (conflict-free), pipelined ----
__global__ __launch_bounds__(256) void k_scores(const float* __restrict__ enc,
                                                const float* __restrict__ g,
                                                const float* __restrict__ c,
                                                float* __restrict__ s) {
  int b = blockIdx.x >> 3, nt = blockIdx.x & 7, t = threadIdx.x;
  int n0 = nt * 256;
  __shared__ float gsm[Hc * Dc];
  __shared__ float csm[Hc];
  __shared__ float el[256 * 33];
  for (int k = t; k < Hc * Dc; k += 256) gsm[k] = g[(size_t)b * Hc * Dc + k];
  if (t < Hc) csm[t] = c[b * Hc + t];
  int row = t >> 3, d4 = t & 7;
  const float* src = enc + ((size_t)b * Nc + n0) * Dc;
  float4 v[8];
  #pragma unroll
  for (int p = 0; p < 8; ++p)
    v[p] = *reinterpret_cast<const float4*>(src + (size_t)(p * 32 + row) * Dc + d4 * 4);
  float acc[Hc] = {};
  for (int ch = 0; ch < 8; ++ch) {
    __syncthreads();  // prior compute done (ch=0: gsm/csm staged)
    #pragma unroll
    for (int p = 0; p < 8; ++p) {
      float* dst = &el[(p * 32 + row) * 33 + d4 * 4];
      dst[0] = v[p].x; dst[1] = v[p].y; dst[2] = v[p].z; dst[3] = v[p].w;
    }
    __syncthreads();  // tile ready
    if (ch < 7) {
      #pragma unroll
      for (int p = 0; p < 8; ++p)
        v[p] = *reinterpret_cast<const float4*>(src + (size_t)(p * 32 + row) * Dc + (ch + 1) * 32 + d4 * 4);
    }
    const float* gb = gsm + ch * 32;
    #pragma unroll
    for (int q = 0; q < 8; ++q) {
      float e0 = el[t * 33 + q * 4 + 0];
      float e1 = el[t * 33 + q * 4 + 1];
      float e2 = el[t * 33 + q * 4 + 2];
      float e3 = el[t * 33 + q * 4 + 3];
      #pragma unroll
      for (int h = 0; h < Hc; ++h) {
        const float4 g4 = *reinterpret_cast<const float4*>(gb + h * Dc + q * 4);
        acc[h] += e0 * g4.x + e1 * g4.y + e2 * g4.z + e3 * g4.w;
      }
    }
  }
  #pragma unroll
  for (int h = 0; h < Hc; ++h)
    s[((size_t)b * Hc + h) * Nc + n0 + t] = kScale * (acc[h] + csm[h]);
}

// ---- fused rowmax + exp + rowsum per (b,h) ----
__global__ __launch_bounds__(256) void k_smax(const float* __restrict__ s,
                                              float* __restrict__ w, float* __restrict__ W0) {
  int bh = blockIdx.x, t = threadIdx.x;
  __shared__ float red[256];
  float lv[8];
  float m = -3.0e38f;
  #pragma unroll
  for (int q = 0; q < 8; ++q) {
    lv[q] = s[(size_t)bh * Nc + q * 256 + t];
    m = fmaxf(m, lv[q]);
  }
  red[t] = m;
  __syncthreads();
  for (int off = 128; off >= 1; off >>= 1) {
    if (t < off) red[t] = fmaxf(red[t], red[t + off]);
    __syncthreads();
  }
  m = red[0];
  __syncthreads();
  float ssum = 0.f;
  #pragma unroll
  for (int q = 0; q < 8; ++q) {
    float e = expf(lv[q] - m);
    w[(size_t)bh * Nc + q * 256 + t] = e;
    ssum += e;
  }
  red[t] = ssum;
  __syncthreads();
  for (int off = 128; off >= 1; off >>= 1) {
    if (t < off) red[t] += red[t + off];
    __syncthreads();
  }
  if (t == 0) W0[bh] = red[0];
}

// ---- S0 partials ----
__global__ __launch_bounds__(256) void k_S0part(const float* __restrict__ enc,
                                                const float* __restrict__ w,
                                                float* __restrict__ Spart) {
  int b = blockIdx.x >> 3, cid = blockIdx.x & 7, t = threadIdx.x;
  __shared__ float wsm[Hc * 256];
  for (int k = t; k < Hc * 256; k += 256) {
    int h = k >> 8, ni = k & 255;
    wsm[k] = w[((size_t)b * Hc + h) * Nc + cid * 256 + ni];
  }
  __syncthreads();
  float acc[Hc] = {};
  const float* ep = enc + ((size_t)b * Nc + cid * 256) * Dc + t;
  for (int ni = 0; ni < 256; ++ni) {
    float ev = ep[(size_t)ni * Dc];
    #pragma unroll
    for (int h = 0; h < Hc; ++h) acc[h] += wsm[h * 256 + ni] * ev;
  }
  #pragma unroll
  for (int h = 0; h < Hc; ++h)
    Spart[(((size_t)b * 8 + cid) * Hc + h) * Dc + t] = acc[h];
}

__global__ __launch_bounds__(256) void k_S0red(const float* __restrict__ Spart,
                                               float* __restrict__ Sacc) {
  int b = blockIdx.x >> 3, h = blockIdx.x & 7, t = threadIdx.x;
  float acc = 0.f;
  for (int cid = 0; cid < 8; ++cid)
    acc += Spart[(((size_t)b * 8 + cid) * Hc + h) * Dc + t];
  Sacc[((size_t)b * Hc + h) * Dc + t] = acc;
}

// ---- per-iteration: rpart[b,h,:] = B_h @ (S_h - removals)/W_h ----
__global__ __launch_bounds__(256) void k_chain(const float* __restrict__ Sacc,
                                               const float* __restrict__ W0,
                                               const float* __restrict__ w,
                                               const float* __restrict__ enc,
                                               const int* __restrict__ hist,
                                               const float* __restrict__ BT,
                                               float* __restrict__ rpart, int tstep) {
  int b = blockIdx.x >> 3, h = blockIdx.x & 7, t = threadIdx.x;
  __shared__ float sh[Dc];
  float se = Sacc[((size_t)b * Hc + h) * Dc + t];
  float Wh = W0[b * Hc + h];
  for (int tt = 0; tt < tstep; ++tt) {
    int j = hist[b * 16 + tt];
    float wv = w[((size_t)b * Hc + h) * Nc + j];
    se -= wv * enc[((size_t)b * Nc + j) * Dc + t];
    Wh -= wv;
  }
  sh[t] = se / Wh;
  __syncthreads();
  float acc = 0.f;
  const float* bt = BT + (size_t)h * Dc * Dc + t;
  #pragma unroll 8
  for (int e = 0; e < Dc; ++e) acc += bt[(size_t)e * Dc] * sh[e];
  rpart[((size_t)b * Hc + h) * Dc + t] = acc;
}

// ---- u scores: thread-owns-n, LDS tile, pipelined ----
__global__ __launch_bounds__(256) void k_uscore(const float* __restrict__ enc,
                                                const float* __restrict__ rpart,
                                                const float* __restrict__ cvec,
                                                float* __restrict__ u) {
  int b = blockIdx.x >> 3, nt = blockIdx.x & 7, t = threadIdx.x;
  int n0 = nt * 256;
  __shared__ float rsm[Dc];
  __shared__ float el[256 * 33];
  {
    float vsum = cvec[t];
    #pragma unroll
    for (int h = 0; h < Hc; ++h) vsum += rpart[((size_t)b * Hc + h) * Dc + t];
    rsm[t] = vsum;
  }
  int row = t >> 3, d4 = t & 7;
  const float* src = enc + ((size_t)b * Nc + n0) * Dc;
  float4 v[8];
  #pragma unroll
  for (int p = 0; p < 8; ++p)
    v[p] = *reinterpret_cast<const float4*>(src + (size_t)(p * 32 + row) * Dc + d4 * 4);
  float acc = 0.f;
  for (int ch = 0; ch < 8; ++ch) {
    __syncthreads();
    #pragma unroll
    for (int p = 0; p < 8; ++p) {
      float* dst = &el[(p * 32 + row) * 33 + d4 * 4];
      dst[0] = v[p].x; dst[1] = v[p].y; dst[2] = v[p].z; dst[3] = v[p].w;
    }
    __syncthreads();
    if (ch < 7) {
      #pragma unroll
      for (int p = 0; p < 8; ++p)
        v[p] = *reinterpret_cast<const float4*>(src + (size_t)(p * 32 + row) * Dc + (ch + 1) * 32 + d4 * 4);
    }
    const float* rb = rsm + ch * 32;
    #pragma unroll
    for (int q = 0; q < 8; ++q) {
      const float4 r4 = *reinterpret_cast<const float4*>(rb + q * 4);
      acc += el[t * 33 + q * 4 + 0] * r4.x + el[t * 33 + q * 4 + 1] * r4.y +
             el[t * 33 + q * 4 + 2] * r4.z + el[t * 33 + q * 4 + 3] * r4.w;
    }
  }
  u[(size_t)b * Nc + n0 + t] = kClip * tanhf(kScale2 * acc);
}

// ---- masked log-softmax + argmax + entropy + outputs ----
__global__ __launch_bounds__(256) void k_select(const float* __restrict__ u,
                                                int* __restrict__ mask, int* __restrict__ hist,
                                                float* __restrict__ out, int tstep) {
  int b = blockIdx.x, t = threadIdx.x;
  __shared__ float red[256];
  __shared__ int redi[256];
  float uval[8];
  float lmax = -3.0e38f;
  int lidx = 0;
  #pragma unroll
  for (int q = 0; q < 8; ++q) {
    int n = t + q * 256;
    float v = u[(size_t)b * Nc + n];
    if (mask[b * Nc + n]) v = kNeg;
    uval[q] = v;
    if (v > lmax) { lmax = v; lidx = n; }
  }
  red[t] = lmax; redi[t] = lidx;
  __syncthreads();
  for (int off = 128; off >= 1; off >>= 1) {
    if (t < off) {
      float o = red[t + off]; int oi = redi[t + off];
      if (o > red[t] || (o == red[t] && oi < redi[t])) { red[t] = o; redi[t] = oi; }
    }
    __syncthreads();
  }
  float mu = red[0];
  int gidx = redi[0];
  __syncthreads();
  float ssum = 0.f;
  #pragma unroll
  for (int q = 0; q < 8; ++q) ssum += expf(uval[q] - mu);
  red[t] = ssum;
  __syncthreads();
  for (int off = 128; off >= 1; off >>= 1) {
    if (t < off) red[t] += red[t + off];
    __syncthreads();
  }
  float Z = red[0];
  float lse = mu + logf(Z);
  __syncthreads();
  float ent = 0.f;
  #pragma unroll
  for (int q = 0; q < 8; ++q) {
    float logp = uval[q] - lse;
    float p = expf(logp);
    if (p > 0.f) ent -= p * logp;
  }
  red[t] = ent;
  __syncthreads();
  for (int off = 128; off >= 1; off >>= 1) {
    if (t < off) red[t] += red[t + off];
    __syncthreads();
  }
  if (t == 0) {
    float enttot = red[0];
    float pi = expf(u[(size_t)b * Nc + gidx] - lse);
    out[b * Sc + tstep] = (float)gidx;
    out[Bc * Sc + b * Sc + tstep] = pi;
    if (tstep == 0) out[2 * Bc * Sc + b] = enttot;
    else out[2 * Bc * Sc + b] += enttot;
    hist[b * 16 + tstep] = gidx;
    mask[b * Nc + gidx] = 1;
  }
}

extern "C" void kernel_launch(void* const* d_in, const int* in_sizes, int n_in,
                              void* d_out, int out_size, void* d_ws, size_t ws_size,
                              hipStream_t stream) {
  (void)in_sizes; (void)n_in; (void)out_size; (void)ws_size;
  const float* enc  = (const float*)d_in[0];
  const float* in_w = (const float*)d_in[1];
  const float* in_b = (const float*)d_in[2];
  const float* ow   = (const float*)d_in[3];
  const float* ob   = (const float*)d_in[4];
  const float* swq  = (const float*)d_in[5];
  const float* swk  = (const float*)d_in[6];
  float* out = (float*)d_out;

  float* ws = (float*)d_ws;
  size_t off = 0;
  auto alloc = [&](size_t n) { float* p = ws + off; off += n; return p; };
  float* hpart = alloc((size_t)Bc * 8 * Dc);
  float* hmean = alloc((size_t)Bc * Dc);
  float* g     = alloc((size_t)Bc * Hc * Dc);
  float* c     = alloc((size_t)Bc * Hc);
  float* s     = alloc((size_t)Bc * Hc * Nc);
  float* w     = alloc((size_t)Bc * Hc * Nc);
  float* W0    = alloc((size_t)Bc * Hc);
  float* Spart = alloc((size_t)Bc * 8 * Hc * Dc);
  float* Sacc  = alloc((size_t)Bc * Hc * Dc);
  float* M1    = alloc((size_t)Dc * Dc);
  float* m1b   = alloc(Dc);
  float* Aout  = alloc((size_t)Dc * Dc);
  float* cvec  = alloc(Dc);
  float* BT    = alloc((size_t)Hc * Dc * Dc);
  float* rpart = alloc((size_t)Bc * Hc * Dc);
  float* u     = alloc((size_t)Bc * Nc);
  int* mask    = (int*)alloc((size_t)Bc * Nc);
  int* hist    = (int*)alloc((size_t)Bc * 16);

  k_hmean_part<<<Bc * 8, 256, 0, stream>>>(enc, hpart);
  k_hmean_red<<<Bc, 256, 0, stream>>>(hpart, hmean);
  k_qgc<<<Bc, 256, 0, stream>>>(hmean, in_w, in_b, g, c);
  k_A1<<<Dc, 256, 0, stream>>>(swq, ow, ob, M1, m1b);
  k_A2<<<Dc, 256, 0, stream>>>(swk, M1, m1b, in_b, Aout, cvec);
  k_A3<<<Hc * 8, 256, 0, stream>>>(Aout, in_w, BT);
  k_scores<<<Bc * 8, 256, 0, stream>>>(enc, g, c, s);
  k_smax<<<Bc * Hc, 256, 0, stream>>>(s, w, W0);
  k_S0part<<<Bc * 8, 256, 0, stream>>>(enc, w, Spart);
  k_S0red<<<Bc * Hc, 256, 0, stream>>>(Spart, Sacc);
  hipMemsetAsync(mask, 0, (size_t)Bc * Nc * sizeof(int), stream);

  for (int t = 0; t < Sc; ++t) {
    k_chain<<<Bc * Hc, 256, 0, stream>>>(Sacc, W0, w, enc, hist, BT, rpart, t);
    k_uscore<<<Bc * 8, 256, 0, stream>>>(enc, rpart, cvec, u);
    k_select<<<Bc, 256, 0, stream>>>(u, mask, hist, out, t);
  }
}